// Round 4
// baseline (692.657 us; speedup 1.0000x reference)
//
#include <hip/hip_runtime.h>

#define BB 32
#define HH 512
#define WW 512
#define HW (HH * WW)
#define NPIX (BB * HH * WW)

#define TILE 64
// phase-A buffer: m over [y0-8..y0+71] x [x0-8..x0+71]; 80 rows, 84-float stride
#define MQ 21            // stride in quads
#define MS 84            // stride in floats
#define MR 80
// phase-B buffer (same LDS, reused in place): e over [y0-4..y0+67] x [x0-4..x0+67]
#define EQ 19            // stride in quads
#define ES 76            // stride in floats

// load 12 consecutive floats (3 quads) from LDS into dst[12]
#define LOADROW12(dst, p4, base)                                              \
    {                                                                         \
        float4 A_ = (p4)[base], B_ = (p4)[(base) + 1], C_ = (p4)[(base) + 2]; \
        (dst)[0] = A_.x; (dst)[1] = A_.y; (dst)[2]  = A_.z; (dst)[3]  = A_.w; \
        (dst)[4] = B_.x; (dst)[5] = B_.y; (dst)[6]  = B_.z; (dst)[7]  = B_.w; \
        (dst)[8] = C_.x; (dst)[9] = C_.y; (dst)[10] = C_.z; (dst)[11] = C_.w; \
    }

// 9x9 blur into acc[4][4]: window rows r0..r0+11, cols 4*c0..4*c0+11 (quads).
// Sliding 12-row register ring; all reg indices compile-time after unroll.
// 8 consecutive lanes read 8 consecutive quads -> conflict-free ds_read_b128.
#define BLUR9(acc, p4, r0, sq, c0)                                            \
    {                                                                         \
        float fw[4][12];                                                      \
        _Pragma("unroll")                                                     \
        for (int j = 0; j < 3; ++j) LOADROW12(fw[j], p4, ((r0) + j) * (sq) + (c0)); \
        _Pragma("unroll")                                                     \
        for (int ky = 0; ky < 9; ++ky) {                                      \
            LOADROW12(fw[(ky + 3) & 3], p4, ((r0) + ky + 3) * (sq) + (c0));   \
            float w[9];                                                       \
            _Pragma("unroll")                                                 \
            for (int kx = 0; kx < 9; ++kx) w[kx] = kw[ky * 9 + kx];           \
            _Pragma("unroll")                                                 \
            for (int my = 0; my < 4; ++my)                                    \
                _Pragma("unroll")                                             \
                for (int kx = 0; kx < 9; ++kx)                                \
                    _Pragma("unroll")                                         \
                    for (int mx = 0; mx < 4; ++mx)                            \
                        acc[my][mx] = fmaf(w[kx], fw[(my + ky) & 3][mx + kx], acc[my][mx]); \
        }                                                                     \
    }

// ---------------------------------------------------------------------------
// k_stats: stage m (80x80) -> blur -> lm on 72x72 (write interior to global)
// -> e = max(q - lm*(2m - lm), 0) in regs -> e into the SAME LDS buffer
// -> blur e -> sigma + per-tile partial sum. m, q, e never touch HBM.
// LDS 26.25 KB -> 5 blocks/CU.
// ---------------------------------------------------------------------------
__global__ __launch_bounds__(256, 5) void k_stats(const float* __restrict__ x,
                                                  const float* __restrict__ kw,
                                                  float* __restrict__ lm,
                                                  float* __restrict__ sg,
                                                  float* __restrict__ psums) {
    __shared__ float smem[MR * MS];
    __shared__ float wsum[4];
    const int tx = threadIdx.x, ty = threadIdx.y;     // 16 x 16
    const int tid = ty * 16 + tx;
    const int x0 = blockIdx.x * TILE, y0 = blockIdx.y * TILE;
    const size_t boff = (size_t)blockIdx.z * HW;
    const float4* x4 = (const float4*)(x + boff * 3);
    float* lmg = lm + boff;

    // ---- stage m over 80 rows x 20 quads (zero outside image) ----
    for (int i = tid; i < MR * 20; i += 256) {
        int r = i / 20, q = i - r * 20;
        int gy = y0 + r - 8, gx = x0 + 4 * q - 8;
        float4 m = make_float4(0.f, 0.f, 0.f, 0.f);
        if (gy >= 0 && gy < HH && gx >= 0 && gx < WW) {
            int go = (gy * WW + gx) >> 2;
            float4 a = x4[3 * go + 0], b = x4[3 * go + 1], c = x4[3 * go + 2];
            const float t = 1.f / 3.f;
            m.x = (a.x + a.y + a.z) * t;
            m.y = (a.w + b.x + b.y) * t;
            m.z = (b.z + b.w + c.x) * t;
            m.w = (c.y + c.z + c.w) * t;
        }
        *(float4*)&smem[r * MS + 4 * q] = m;
    }
    __syncthreads();

    const float4* m4 = (const float4*)smem;

    // micro-tile t of 324 (18x18): lm rows y0-4+4tr.., col quad q0 (origin -4)
    auto tileA = [&](int t, float (&eo)[4][4]) {
        int tr = t / 18, q0 = t - tr * 18;
        float acc[4][4] = {};
        BLUR9(acc, m4, 4 * tr, MQ, q0);
        const int X0 = x0 - 4 + 4 * q0;               // 16B-aligned (quad in/out)
        const bool cin = (X0 >= 0) && (X0 < WW);
        const bool wlm = (tr >= 1) && (tr <= 16) && (q0 >= 1) && (q0 <= 16);
#pragma unroll
        for (int row = 0; row < 4; ++row) {
            int Y = y0 - 4 + 4 * tr + row;
            float4 l = make_float4(acc[row][0], acc[row][1], acc[row][2], acc[row][3]);
            if (wlm) *(float4*)(lmg + (size_t)Y * WW + X0) = l;
            float4 e = make_float4(0.f, 0.f, 0.f, 0.f);
            if (cin && Y >= 0 && Y < HH) {
                float4 mm = *(const float4*)&smem[(4 * tr + row + 4) * MS + 4 * (q0 + 1)];
                int go = (Y * WW + X0) >> 2;
                float4 a = x4[3 * go + 0], b = x4[3 * go + 1], c = x4[3 * go + 2];
                const float t3 = 1.f / 3.f;
                float4 qv;
                qv.x = (a.x * a.x + a.y * a.y + a.z * a.z) * t3;
                qv.y = (a.w * a.w + b.x * b.x + b.y * b.y) * t3;
                qv.z = (b.z * b.z + b.w * b.w + c.x * c.x) * t3;
                qv.w = (c.y * c.y + c.z * c.z + c.w * c.w) * t3;
                e.x = fmaxf(qv.x - l.x * (2.f * mm.x - l.x), 0.f);
                e.y = fmaxf(qv.y - l.y * (2.f * mm.y - l.y), 0.f);
                e.z = fmaxf(qv.z - l.z * (2.f * mm.z - l.z), 0.f);
                e.w = fmaxf(qv.w - l.w * (2.f * mm.w - l.w), 0.f);
            }
            eo[row][0] = e.x; eo[row][1] = e.y; eo[row][2] = e.z; eo[row][3] = e.w;
        }
    };

    // pass A1: tiles 0..255 (tr<=14 -> e rows<=59 -> ES-floats<=4499)
    float e1[4][4];
    tileA(tid, e1);
    __syncthreads();                                  // all A1 m-reads done

    // e1 -> LDS (phase-B layout). Disjoint from A2's m-reads (MS-floats>=4704).
    {
        int tr = tid / 18, q0 = tid - tr * 18;
#pragma unroll
        for (int row = 0; row < 4; ++row)
            *(float4*)&smem[(4 * tr + row) * ES + 4 * q0] =
                make_float4(e1[row][0], e1[row][1], e1[row][2], e1[row][3]);
    }
    // pass A2: tiles 256..323 (tr=14..17), threads 0..67
    float e2[4][4];
    if (tid < 68) tileA(256 + tid, e2);
    __syncthreads();                                  // A2 m-reads done; e1 visible
    if (tid < 68) {
        int t = 256 + tid, tr = t / 18, q0 = t - tr * 18;
#pragma unroll
        for (int row = 0; row < 4; ++row)
            *(float4*)&smem[(4 * tr + row) * ES + 4 * q0] =
                make_float4(e2[row][0], e2[row][1], e2[row][2], e2[row][3]);
    }
    __syncthreads();                                  // all e staged

    // ---- blur e -> sigma on the 64x64 interior ----
    const float4* e4s = (const float4*)smem;
    float acc[4][4] = {};
    BLUR9(acc, e4s, 4 * ty, EQ, tx);

    float s = 0.f;
    float* dp = sg + boff + (size_t)(y0 + 4 * ty) * WW + x0 + 4 * tx;
#pragma unroll
    for (int my = 0; my < 4; ++my) {
        float4 o;
        o.x = sqrtf(fmaxf(acc[my][0], 0.f));
        o.y = sqrtf(fmaxf(acc[my][1], 0.f));
        o.z = sqrtf(fmaxf(acc[my][2], 0.f));
        o.w = sqrtf(fmaxf(acc[my][3], 0.f));
        *(float4*)(dp + my * WW) = o;
        s += o.x + o.y + o.z + o.w;
    }
#pragma unroll
    for (int off = 32; off > 0; off >>= 1) s += __shfl_down(s, off);
    if ((tid & 63) == 0) wsum[tid >> 6] = s;
    __syncthreads();
    if (tid == 0)
        psums[blockIdx.z * 64 + blockIdx.y * 8 + blockIdx.x] =
            wsum[0] + wsum[1] + wsum[2] + wsum[3];
}

// ---------------------------------------------------------------------------
// k_norm: out = (x - lm) / max(mean_sigma_b, sigma); in-block psums reduction.
// ---------------------------------------------------------------------------
__global__ __launch_bounds__(256) void k_norm(const float4* __restrict__ x4,
                                              const float4* __restrict__ lm4,
                                              const float4* __restrict__ sg4,
                                              const float* __restrict__ psums,
                                              float4* __restrict__ out4) {
    __shared__ float msh;
    int g = blockIdx.x * 256 + threadIdx.x;
    int b = g >> 16;                                  // g / (HW/4); uniform per block
    float s = 0.f;
    if (threadIdx.x < 64) s = psums[b * 64 + threadIdx.x];
#pragma unroll
    for (int off = 32; off > 0; off >>= 1) s += __shfl_down(s, off);
    if (threadIdx.x == 0) msh = s * (1.f / (float)HW);
    __syncthreads();
    float ms = msh;

    float4 l = lm4[g];
    float4 sv = sg4[g];
    float i0 = 1.f / fmaxf(ms, sv.x);
    float i1 = 1.f / fmaxf(ms, sv.y);
    float i2 = 1.f / fmaxf(ms, sv.z);
    float i3 = 1.f / fmaxf(ms, sv.w);
    float4 a = x4[3 * g + 0];
    float4 bb = x4[3 * g + 1];
    float4 c = x4[3 * g + 2];
    float4 o0, o1, o2;
    o0.x = (a.x - l.x) * i0;  o0.y = (a.y - l.x) * i0;  o0.z = (a.z - l.x) * i0;
    o0.w = (a.w - l.y) * i1;  o1.x = (bb.x - l.y) * i1; o1.y = (bb.y - l.y) * i1;
    o1.z = (bb.z - l.z) * i2; o1.w = (bb.w - l.z) * i2; o2.x = (c.x - l.z) * i2;
    o2.y = (c.y - l.w) * i3;  o2.z = (c.z - l.w) * i3;  o2.w = (c.w - l.w) * i3;
    out4[3 * g + 0] = o0;
    out4[3 * g + 1] = o1;
    out4[3 * g + 2] = o2;
}

extern "C" void kernel_launch(void* const* d_in, const int* in_sizes, int n_in,
                              void* d_out, int out_size, void* d_ws, size_t ws_size,
                              hipStream_t stream) {
    const float* x = (const float*)d_in[0];
    const float* kw = (const float*)d_in[1];
    float* out = (float*)d_out;
    float* wsp = (float*)d_ws;
    float* lmb = wsp;                                 // NPIX floats
    float* sgb = wsp + (size_t)NPIX;                  // NPIX floats
    float* ps  = wsp + 2 * (size_t)NPIX;              // 2048 floats

    dim3 blk(16, 16);
    dim3 grd(WW / TILE, HH / TILE, BB);
    k_stats<<<grd, blk, 0, stream>>>(x, kw, lmb, sgb, ps);

    k_norm<<<NPIX / 4 / 256, 256, 0, stream>>>((const float4*)x, (const float4*)lmb,
                                               (const float4*)sgb, ps, (float4*)out);
}

// Round 5
// 348.846 us; speedup vs baseline: 1.9856x; 1.9856x over previous
//
#include <hip/hip_runtime.h>

#define BB 32
#define HH 512
#define WW 512
#define HW (HH * WW)
#define NPIX (BB * HH * WW)

#define TILE 64
// m buffer: mean over [y0-8..y0+71] x [x0-8..x0+71]; 80 rows, 84-float stride
#define MQ 21            // stride in quads
#define MS 84            // stride in floats
#define MR 80
// e buffer (separate LDS): e over [y0-4..y0+67] x [x0-4..x0+67]; 76-float stride
#define EQ 19            // stride in quads
#define ES 76            // stride in floats

// load 12 consecutive floats (3 quads) from LDS into dst[12]
#define LOADROW12(dst, p4, base)                                              \
    {                                                                         \
        float4 A_ = (p4)[base], B_ = (p4)[(base) + 1], C_ = (p4)[(base) + 2]; \
        (dst)[0] = A_.x; (dst)[1] = A_.y; (dst)[2]  = A_.z; (dst)[3]  = A_.w; \
        (dst)[4] = B_.x; (dst)[5] = B_.y; (dst)[6]  = B_.z; (dst)[7]  = B_.w; \
        (dst)[8] = C_.x; (dst)[9] = C_.y; (dst)[10] = C_.z; (dst)[11] = C_.w; \
    }

// 9x9 blur into acc[4][4]: window rows r0..r0+11, col quads c0..c0+2.
// Sliding 12-row register ring; all reg indices compile-time after unroll.
#define BLUR9(acc, p4, r0, sq, c0)                                            \
    {                                                                         \
        float fw[4][12];                                                      \
        _Pragma("unroll")                                                     \
        for (int j = 0; j < 3; ++j) LOADROW12(fw[j], p4, ((r0) + j) * (sq) + (c0)); \
        _Pragma("unroll")                                                     \
        for (int ky = 0; ky < 9; ++ky) {                                      \
            LOADROW12(fw[(ky + 3) & 3], p4, ((r0) + ky + 3) * (sq) + (c0));   \
            float w[9];                                                       \
            _Pragma("unroll")                                                 \
            for (int kx = 0; kx < 9; ++kx) w[kx] = kw[ky * 9 + kx];           \
            _Pragma("unroll")                                                 \
            for (int my = 0; my < 4; ++my)                                    \
                _Pragma("unroll")                                             \
                for (int kx = 0; kx < 9; ++kx)                                \
                    _Pragma("unroll")                                         \
                    for (int mx = 0; mx < 4; ++mx)                            \
                        acc[my][mx] = fmaf(w[kx], fw[(my + ky) & 3][mx + kx], acc[my][mx]); \
        }                                                                     \
    }

// ---------------------------------------------------------------------------
// k_stats: stage m (80x80) -> blur m -> lm (write interior) + e into a
// SEPARATE LDS buffer (no cross-barrier register state, body emitted once)
// -> blur e -> sigma + per-tile partial sum. m,q,e never touch HBM.
// LDS 48.8 KB -> 3 blocks/CU.
// ---------------------------------------------------------------------------
__global__ __launch_bounds__(256) void k_stats(const float* __restrict__ x,
                                               const float* __restrict__ kw,
                                               float* __restrict__ lm,
                                               float* __restrict__ sg,
                                               float* __restrict__ psums) {
    __shared__ float mt[MR * MS];
    __shared__ float et[72 * ES];
    __shared__ float wsum[4];
    const int tx = threadIdx.x, ty = threadIdx.y;     // 16 x 16
    const int tid = ty * 16 + tx;
    const int x0 = blockIdx.x * TILE, y0 = blockIdx.y * TILE;
    const size_t boff = (size_t)blockIdx.z * HW;
    const float4* x4 = (const float4*)(x + boff * 3);
    float* lmg = lm + boff;

    // ---- stage m over 80 rows x 20 quads (zero outside image) ----
    for (int i = tid; i < MR * 20; i += 256) {
        int r = i / 20, q = i - r * 20;
        int gy = y0 + r - 8, gx = x0 + 4 * q - 8;
        float4 m = make_float4(0.f, 0.f, 0.f, 0.f);
        if (gy >= 0 && gy < HH && gx >= 0 && gx < WW) {
            int go = (gy * WW + gx) >> 2;
            float4 a = x4[3 * go + 0], b = x4[3 * go + 1], c = x4[3 * go + 2];
            const float t = 1.f / 3.f;
            m.x = (a.x + a.y + a.z) * t;
            m.y = (a.w + b.x + b.y) * t;
            m.z = (b.z + b.w + c.x) * t;
            m.w = (c.y + c.z + c.w) * t;
        }
        *(float4*)&mt[r * MS + 4 * q] = m;
    }
    __syncthreads();

    const float4* m4 = (const float4*)mt;

    // ---- pass A: 324 micro-tiles (18x18) over 2 iterations; each body is
    // self-contained (blur -> lm global write -> e -> e-LDS write).
#pragma unroll 1
    for (int it = 0; it < 2; ++it) {
        int t = tid + 256 * it;
        if (t < 324) {
            int tr = t / 18, q0 = t - tr * 18;
            float acc[4][4] = {};
            BLUR9(acc, m4, 4 * tr, MQ, q0);
            const int X0 = x0 - 4 + 4 * q0;           // 16B-aligned
            const bool cin = (X0 >= 0) && (X0 < WW);
            const bool wlm = (tr >= 1) && (tr <= 16) && (q0 >= 1) && (q0 <= 16);
#pragma unroll
            for (int row = 0; row < 4; ++row) {
                int Y = y0 - 4 + 4 * tr + row;
                float4 l = make_float4(acc[row][0], acc[row][1], acc[row][2], acc[row][3]);
                if (wlm) *(float4*)(lmg + (size_t)Y * WW + X0) = l;
                float4 e = make_float4(0.f, 0.f, 0.f, 0.f);
                if (cin && Y >= 0 && Y < HH) {
                    float4 mm = *(const float4*)&mt[(4 * tr + row + 4) * MS + 4 * (q0 + 1)];
                    int go = (Y * WW + X0) >> 2;
                    float4 a = x4[3 * go + 0], b = x4[3 * go + 1], c = x4[3 * go + 2];
                    const float t3 = 1.f / 3.f;
                    float4 qv;
                    qv.x = (a.x * a.x + a.y * a.y + a.z * a.z) * t3;
                    qv.y = (a.w * a.w + b.x * b.x + b.y * b.y) * t3;
                    qv.z = (b.z * b.z + b.w * b.w + c.x * c.x) * t3;
                    qv.w = (c.y * c.y + c.z * c.z + c.w * c.w) * t3;
                    e.x = fmaxf(qv.x - l.x * (2.f * mm.x - l.x), 0.f);
                    e.y = fmaxf(qv.y - l.y * (2.f * mm.y - l.y), 0.f);
                    e.z = fmaxf(qv.z - l.z * (2.f * mm.z - l.z), 0.f);
                    e.w = fmaxf(qv.w - l.w * (2.f * mm.w - l.w), 0.f);
                }
                *(float4*)&et[(4 * tr + row) * ES + 4 * q0] = e;  // different buffer: no hazard
            }
        }
    }
    __syncthreads();                                  // all e staged

    // ---- blur e -> sigma on the 64x64 interior ----
    const float4* e4s = (const float4*)et;
    float acc[4][4] = {};
    BLUR9(acc, e4s, 4 * ty, EQ, tx);

    float s = 0.f;
    float* dp = sg + boff + (size_t)(y0 + 4 * ty) * WW + x0 + 4 * tx;
#pragma unroll
    for (int my = 0; my < 4; ++my) {
        float4 o;
        o.x = sqrtf(fmaxf(acc[my][0], 0.f));
        o.y = sqrtf(fmaxf(acc[my][1], 0.f));
        o.z = sqrtf(fmaxf(acc[my][2], 0.f));
        o.w = sqrtf(fmaxf(acc[my][3], 0.f));
        *(float4*)(dp + my * WW) = o;
        s += o.x + o.y + o.z + o.w;
    }
#pragma unroll
    for (int off = 32; off > 0; off >>= 1) s += __shfl_down(s, off);
    if ((tid & 63) == 0) wsum[tid >> 6] = s;
    __syncthreads();
    if (tid == 0)
        psums[blockIdx.z * 64 + blockIdx.y * 8 + blockIdx.x] =
            wsum[0] + wsum[1] + wsum[2] + wsum[3];
}

// ---------------------------------------------------------------------------
// k_norm: out = (x - lm) / max(mean_sigma_b, sigma); in-block psums reduction.
// ---------------------------------------------------------------------------
__global__ __launch_bounds__(256) void k_norm(const float4* __restrict__ x4,
                                              const float4* __restrict__ lm4,
                                              const float4* __restrict__ sg4,
                                              const float* __restrict__ psums,
                                              float4* __restrict__ out4) {
    __shared__ float msh;
    int g = blockIdx.x * 256 + threadIdx.x;
    int b = g >> 16;                                  // g / (HW/4); uniform per block
    float s = 0.f;
    if (threadIdx.x < 64) s = psums[b * 64 + threadIdx.x];
#pragma unroll
    for (int off = 32; off > 0; off >>= 1) s += __shfl_down(s, off);
    if (threadIdx.x == 0) msh = s * (1.f / (float)HW);
    __syncthreads();
    float ms = msh;

    float4 l = lm4[g];
    float4 sv = sg4[g];
    float i0 = 1.f / fmaxf(ms, sv.x);
    float i1 = 1.f / fmaxf(ms, sv.y);
    float i2 = 1.f / fmaxf(ms, sv.z);
    float i3 = 1.f / fmaxf(ms, sv.w);
    float4 a = x4[3 * g + 0];
    float4 bb = x4[3 * g + 1];
    float4 c = x4[3 * g + 2];
    float4 o0, o1, o2;
    o0.x = (a.x - l.x) * i0;  o0.y = (a.y - l.x) * i0;  o0.z = (a.z - l.x) * i0;
    o0.w = (a.w - l.y) * i1;  o1.x = (bb.x - l.y) * i1; o1.y = (bb.y - l.y) * i1;
    o1.z = (bb.z - l.z) * i2; o1.w = (bb.w - l.z) * i2; o2.x = (c.x - l.z) * i2;
    o2.y = (c.y - l.w) * i3;  o2.z = (c.z - l.w) * i3;  o2.w = (c.w - l.w) * i3;
    out4[3 * g + 0] = o0;
    out4[3 * g + 1] = o1;
    out4[3 * g + 2] = o2;
}

extern "C" void kernel_launch(void* const* d_in, const int* in_sizes, int n_in,
                              void* d_out, int out_size, void* d_ws, size_t ws_size,
                              hipStream_t stream) {
    const float* x = (const float*)d_in[0];
    const float* kw = (const float*)d_in[1];
    float* out = (float*)d_out;
    float* wsp = (float*)d_ws;
    float* lmb = wsp;                                 // NPIX floats
    float* sgb = wsp + (size_t)NPIX;                  // NPIX floats
    float* ps  = wsp + 2 * (size_t)NPIX;              // 2048 floats

    dim3 blk(16, 16);
    dim3 grd(WW / TILE, HH / TILE, BB);
    k_stats<<<grd, blk, 0, stream>>>(x, kw, lmb, sgb, ps);

    k_norm<<<NPIX / 4 / 256, 256, 0, stream>>>((const float4*)x, (const float4*)lmb,
                                               (const float4*)sgb, ps, (float4*)out);
}